// Round 2
// baseline (3749.557 us; speedup 1.0000x reference)
//
#include <hip/hip_runtime.h>

#define DEPTHL 8
#define BZ 8
#define SEQ 1024
#define CDIM 768
#define HEADS 12
#define HDIM 64
#define MLPD 3072
#define TOK (BZ*SEQ)      // 8192
#define QKVN (3*CDIM)     // 2304

typedef __attribute__((ext_vector_type(8))) short vshort8;
typedef __attribute__((ext_vector_type(4))) short vshort4;
typedef __attribute__((ext_vector_type(4))) float vfloat4;

__device__ __forceinline__ short bf16_bits(float f) {
  union { float f; unsigned u; } x; x.f = f;
  unsigned r = (x.u + 0x7FFFu + ((x.u >> 16) & 1u)) >> 16;
  return (short)r;
}
__device__ __forceinline__ float bits_to_f(short s) {
  union { unsigned u; float f; } x; x.u = ((unsigned)(unsigned short)s) << 16;
  return x.f;
}

#define GL16(g, l) __builtin_amdgcn_global_load_lds( \
    (const __attribute__((address_space(1))) unsigned int*)(g), \
    (__attribute__((address_space(3))) unsigned int*)(l), 16, 0, 0)

// ---------------- weight convert + transpose: fp32 [D][K][N] -> bf16 [D][N][K]
__global__ __launch_bounds__(256) void wconv_t(const float* __restrict__ in,
                                               short* __restrict__ out,
                                               int K, int N) {
  __shared__ float tile[32][33];
  const long d = blockIdx.z;
  in  += d * (long)K * N;
  out += d * (long)N * K;
  const int n0 = blockIdx.x * 32, k0 = blockIdx.y * 32;
  const int tx = threadIdx.x & 31, ty = threadIdx.x >> 5;
#pragma unroll
  for (int i = 0; i < 4; i++)
    tile[ty + 8*i][tx] = in[(long)(k0 + ty + 8*i) * N + n0 + tx];
  __syncthreads();
#pragma unroll
  for (int i = 0; i < 4; i++)
    out[(long)(n0 + ty + 8*i) * K + k0 + tx] = bf16_bits(tile[tx][ty + 8*i]);
}

// ---------------- LayerNorm: fp32 h row -> bf16 y row
__global__ __launch_bounds__(192) void ln_fwd(const float* __restrict__ h,
                                              const float* __restrict__ g,
                                              const float* __restrict__ be,
                                              short* __restrict__ y) {
  __shared__ float red[3];
  const int row = blockIdx.x;
  const int tid = threadIdx.x;
  const float4 v = ((const float4*)(h + (long)row * CDIM))[tid];
  float s = v.x + v.y + v.z + v.w;
#pragma unroll
  for (int m = 32; m >= 1; m >>= 1) s += __shfl_xor(s, m);
  if ((tid & 63) == 0) red[tid >> 6] = s;
  __syncthreads();
  const float mu = (red[0] + red[1] + red[2]) * (1.0f / CDIM);
  float dx = v.x - mu, dy = v.y - mu, dz = v.z - mu, dw = v.w - mu;
  float q = dx*dx + dy*dy + dz*dz + dw*dw;
  __syncthreads();
#pragma unroll
  for (int m = 32; m >= 1; m >>= 1) q += __shfl_xor(q, m);
  if ((tid & 63) == 0) red[tid >> 6] = q;
  __syncthreads();
  const float rstd = rsqrtf((red[0] + red[1] + red[2]) * (1.0f / CDIM) + 1e-5f);
  const float4 g4 = ((const float4*)g)[tid];
  const float4 b4 = ((const float4*)be)[tid];
  vshort4 o;
  o[0] = bf16_bits(dx * rstd * g4.x + b4.x);
  o[1] = bf16_bits(dy * rstd * g4.y + b4.y);
  o[2] = bf16_bits(dz * rstd * g4.z + b4.z);
  o[3] = bf16_bits(dw * rstd * g4.w + b4.w);
  *(vshort4*)(y + (long)row * CDIM + tid * 4) = o;
}

// ---------------- GEMM: C[M,N] = A[M,K] @ Bt[N,K]^T  (m97-style 128x128, BK=32)
// EPI: 0 = store bf16, 1 = bias+relu -> bf16, 2 = bias + residual add into fp32 C
template<int EPI>
__global__ __launch_bounds__(256) void gemm_bt(const short* __restrict__ A,
                                               const short* __restrict__ Bt,
                                               const float* __restrict__ bias,
                                               void* __restrict__ Cout,
                                               int M, int N, int K) {
  __shared__ short As[128 * 32];
  __shared__ short Bs[128 * 32];
  const int tid = threadIdx.x;
  const int wid = tid >> 6, lane = tid & 63;
  const int lg = lane >> 4, lr = lane & 15;
  const int wm = wid >> 1, wn = wid & 1;
  const long by = blockIdx.y;
  const long bx = blockIdx.x;

  vfloat4 acc[4][4];
#pragma unroll
  for (int i = 0; i < 4; i++)
#pragma unroll
    for (int j = 0; j < 4; j++) acc[i][j] = (vfloat4){0.f, 0.f, 0.f, 0.f};

  const int c = wid * 64 + lane;           // staging chunk id, 16B each
  const short* Ag0 = A  + (by * 128 +      (c >> 2)) * (long)K + (c & 3) * 8;
  const short* Ag1 = A  + (by * 128 + 64 + (c >> 2)) * (long)K + (c & 3) * 8;
  const short* Bg0 = Bt + (bx * 128 +      (c >> 2)) * (long)K + (c & 3) * 8;
  const short* Bg1 = Bt + (bx * 128 + 64 + (c >> 2)) * (long)K + (c & 3) * 8;
  short* Al = As + c * 8;
  short* Bl = Bs + c * 8;

  for (int kk = 0; kk < K; kk += 32) {
    __syncthreads();
    GL16(Ag0 + kk, Al);
    GL16(Ag1 + kk, Al + 2048);
    GL16(Bg0 + kk, Bl);
    GL16(Bg1 + kk, Bl + 2048);
    __syncthreads();
    vshort8 a[4], b[4];
#pragma unroll
    for (int mt = 0; mt < 4; mt++)
      a[mt] = *(const vshort8*)(As + (wm * 64 + mt * 16 + lr) * 32 + lg * 8);
#pragma unroll
    for (int nt = 0; nt < 4; nt++)
      b[nt] = *(const vshort8*)(Bs + (wn * 64 + nt * 16 + lr) * 32 + lg * 8);
#pragma unroll
    for (int mt = 0; mt < 4; mt++)
#pragma unroll
      for (int nt = 0; nt < 4; nt++)
        acc[mt][nt] = __builtin_amdgcn_mfma_f32_16x16x32_bf16(a[mt], b[nt], acc[mt][nt], 0, 0, 0);
  }

  const long row0 = by * 128 + wm * 64;
  const long col0 = bx * 128 + wn * 64;
#pragma unroll
  for (int mt = 0; mt < 4; mt++) {
#pragma unroll
    for (int nt = 0; nt < 4; nt++) {
      const long col = col0 + nt * 16 + lr;
      float bv = 0.f;
      if (EPI != 0) bv = bias[col];
#pragma unroll
      for (int r = 0; r < 4; r++) {
        const long row = row0 + mt * 16 + lg * 4 + r;
        float v = acc[mt][nt][r];
        if (EPI == 0) {
          ((short*)Cout)[row * N + col] = bf16_bits(v);
        } else if (EPI == 1) {
          v += bv; v = v > 0.f ? v : 0.f;
          ((short*)Cout)[row * N + col] = bf16_bits(v);
        } else {
          float* hp = (float*)Cout + row * N + col;
          *hp = *hp + v + bv;
        }
      }
    }
  }
}

// ---------------- fused attention with exact double softmax
// grid: (SEQ/16, BZ*HEADS); 256 threads (4 waves). Per block: 16 q-rows of one head.
__global__ __launch_bounds__(256) void attn_fused(const short* __restrict__ qkv,
                                                  short* __restrict__ o) {
  __shared__ short Sb[16 * 1024];   // bf16 scores, XOR-swizzled rows
  __shared__ short vT[64 * 72];     // v^T tile [d][kv], padded stride 72
  const int qt = blockIdx.x;
  const int bh = blockIdx.y;
  const int b = bh / HEADS, hh = bh % HEADS;
  const int tid = threadIdx.x, wid = tid >> 6, lane = tid & 63;
  const int lg = lane >> 4, lr = lane & 15;
  const long tokbase = (long)b * SEQ;
  const short* qbase = qkv + tokbase * QKVN + hh * HDIM;
  const short* kbase = qbase + CDIM;
  const short* vbase = qbase + 2 * CDIM;

  // Q fragments (A operand), kept in registers
  vshort8 qf[2];
#pragma unroll
  for (int ks = 0; ks < 2; ks++)
    qf[ks] = *(const vshort8*)(qbase + (long)(qt * 16 + lr) * QKVN + ks * 32 + lg * 8);

  // ---- Phase 1: S = q @ k^T * scale  -> Sb (bf16, swizzled)
  for (int i = 0; i < 16; i++) {
    const int n0 = (wid + 4 * i) * 16;
    vfloat4 s = (vfloat4){0.f, 0.f, 0.f, 0.f};
#pragma unroll
    for (int ks = 0; ks < 2; ks++) {
      vshort8 kf = *(const vshort8*)(kbase + (long)(n0 + lr) * QKVN + ks * 32 + lg * 8);
      s = __builtin_amdgcn_mfma_f32_16x16x32_bf16(qf[ks], kf, s, 0, 0, 0);
    }
#pragma unroll
    for (int r = 0; r < 4; r++) {
      const int row = lg * 4 + r;
      const int byt = ((row * 1024 + n0 + lr) * 2) ^ ((row & 7) << 4);
      *(short*)((char*)Sb + byt) = bf16_bits(s[r] * 0.125f);
    }
  }
  __syncthreads();

  // ---- Phase 2: double softmax per row (wave-parallel; order-agnostic in-place)
#pragma unroll
  for (int rr = 0; rr < 4; rr++) {
    const int row = wid * 4 + rr;
    const int base = row * 2048 + lane * 32;
    const int swz = (row & 7) << 4;
    vshort8 e0 = *(const vshort8*)((char*)Sb + (base ^ swz));
    vshort8 e1 = *(const vshort8*)((char*)Sb + ((base + 16) ^ swz));
    float x[16];
#pragma unroll
    for (int j = 0; j < 8; j++) { x[j] = bits_to_f(e0[j]); x[8 + j] = bits_to_f(e1[j]); }
    float m = x[0];
#pragma unroll
    for (int j = 1; j < 16; j++) m = fmaxf(m, x[j]);
#pragma unroll
    for (int sh = 1; sh < 64; sh <<= 1) m = fmaxf(m, __shfl_xor(m, sh));
    float z = 0.f;
#pragma unroll
    for (int j = 0; j < 16; j++) { x[j] = __expf(x[j] - m); z += x[j]; }
#pragma unroll
    for (int sh = 1; sh < 64; sh <<= 1) z += __shfl_xor(z, sh);
    const float rz = 1.0f / z;
    float t2 = 0.f;
#pragma unroll
    for (int j = 0; j < 16; j++) { x[j] = __expf(x[j] * rz); t2 += x[j]; }
#pragma unroll
    for (int sh = 1; sh < 64; sh <<= 1) t2 += __shfl_xor(t2, sh);
    const float rt = 1.0f / t2;
    vshort8 o0, o1;
#pragma unroll
    for (int j = 0; j < 8; j++) { o0[j] = bf16_bits(x[j] * rt); o1[j] = bf16_bits(x[8 + j] * rt); }
    *(vshort8*)((char*)Sb + (base ^ swz)) = o0;
    *(vshort8*)((char*)Sb + ((base + 16) ^ swz)) = o1;
  }

  // ---- Phase 3: O = A @ V (stage v^T per 64-kv tile, conflict-free layout)
  vfloat4 oacc = (vfloat4){0.f, 0.f, 0.f, 0.f};
  for (int kt = 0; kt < 16; kt++) {
    const int d0 = (tid & 7) * 8;
    const int kvp = (tid >> 3) * 2;
    const short* vr = vbase + (long)(kt * 64 + kvp) * QKVN + d0;
    vshort8 v0 = *(const vshort8*)vr;
    vshort8 v1 = *(const vshort8*)(vr + QKVN);
    __syncthreads();   // prev-tile MFMA readers done (kt=0: phase-2 writes done)
#pragma unroll
    for (int j = 0; j < 8; j++) {
      unsigned pk = ((unsigned)(unsigned short)v0[j]) | (((unsigned)(unsigned short)v1[j]) << 16);
      *(unsigned*)((char*)vT + ((d0 + j) * 72 + kvp) * 2) = pk;
    }
    __syncthreads();
#pragma unroll
    for (int ks = 0; ks < 2; ks++) {
      const int kv0 = kt * 64 + ks * 32;
      const int abyt = ((lr * 1024 + kv0 + lg * 8) * 2) ^ ((lr & 7) << 4);
      vshort8 af = *(const vshort8*)((char*)Sb + abyt);
      vshort8 bfr = *(const vshort8*)(vT + (wid * 16 + lr) * 72 + ks * 32 + lg * 8);
      oacc = __builtin_amdgcn_mfma_f32_16x16x32_bf16(af, bfr, oacc, 0, 0, 0);
    }
  }

#pragma unroll
  for (int r = 0; r < 4; r++) {
    const long row = tokbase + qt * 16 + lg * 4 + r;
    o[row * CDIM + hh * HDIM + wid * 16 + lr] = bf16_bits(oacc[r]);
  }
}

extern "C" void kernel_launch(void* const* d_in, const int* in_sizes, int n_in,
                              void* d_out, int out_size, void* d_ws, size_t ws_size,
                              hipStream_t stream) {
  const float* x     = (const float*)d_in[0];
  const float* ln1_g = (const float*)d_in[1];
  const float* ln1_b = (const float*)d_in[2];
  const float* wqkv  = (const float*)d_in[3];
  const float* wproj = (const float*)d_in[4];
  const float* bproj = (const float*)d_in[5];
  const float* ln2_g = (const float*)d_in[6];
  const float* ln2_b = (const float*)d_in[7];
  const float* w1    = (const float*)d_in[8];
  const float* b1    = (const float*)d_in[9];
  const float* w2    = (const float*)d_in[10];
  const float* b2    = (const float*)d_in[11];
  float* h = (float*)d_out;

  char* ws = (char*)d_ws;
  short* wqkv_t  = (short*)ws; ws += (size_t)DEPTHL * QKVN * CDIM * 2;
  short* wproj_t = (short*)ws; ws += (size_t)DEPTHL * CDIM * CDIM * 2;
  short* w1_t    = (short*)ws; ws += (size_t)DEPTHL * MLPD * CDIM * 2;
  short* w2_t    = (short*)ws; ws += (size_t)DEPTHL * CDIM * MLPD * 2;
  short* ybf     = (short*)ws; ws += (size_t)TOK * CDIM * 2;
  short* qkvbf   = (short*)ws; ws += (size_t)TOK * QKVN * 2;
  short* obf     = (short*)ws; ws += (size_t)TOK * CDIM * 2;
  short* f1bf    = (short*)ws; ws += (size_t)TOK * MLPD * 2;

  hipMemcpyAsync(h, x, (size_t)TOK * CDIM * sizeof(float), hipMemcpyDeviceToDevice, stream);

  wconv_t<<<dim3(QKVN / 32, CDIM / 32, DEPTHL), 256, 0, stream>>>(wqkv, wqkv_t, CDIM, QKVN);
  wconv_t<<<dim3(CDIM / 32, CDIM / 32, DEPTHL), 256, 0, stream>>>(wproj, wproj_t, CDIM, CDIM);
  wconv_t<<<dim3(MLPD / 32, CDIM / 32, DEPTHL), 256, 0, stream>>>(w1, w1_t, CDIM, MLPD);
  wconv_t<<<dim3(CDIM / 32, MLPD / 32, DEPTHL), 256, 0, stream>>>(w2, w2_t, MLPD, CDIM);

  for (int l = 0; l < DEPTHL; l++) {
    ln_fwd<<<TOK, 192, 0, stream>>>(h, ln1_g + l * CDIM, ln1_b + l * CDIM, ybf);
    gemm_bt<0><<<dim3(QKVN / 128, TOK / 128), 256, 0, stream>>>(
        ybf, wqkv_t + (size_t)l * QKVN * CDIM, nullptr, qkvbf, TOK, QKVN, CDIM);
    attn_fused<<<dim3(SEQ / 16, BZ * HEADS), 256, 0, stream>>>(qkvbf, obf);
    gemm_bt<2><<<dim3(CDIM / 128, TOK / 128), 256, 0, stream>>>(
        obf, wproj_t + (size_t)l * CDIM * CDIM, bproj + l * CDIM, h, TOK, CDIM, CDIM);
    ln_fwd<<<TOK, 192, 0, stream>>>(h, ln2_g + l * CDIM, ln2_b + l * CDIM, ybf);
    gemm_bt<1><<<dim3(MLPD / 128, TOK / 128), 256, 0, stream>>>(
        ybf, w1_t + (size_t)l * MLPD * CDIM, b1 + l * MLPD, f1bf, TOK, MLPD, CDIM);
    gemm_bt<2><<<dim3(CDIM / 128, TOK / 128), 256, 0, stream>>>(
        f1bf, w2_t + (size_t)l * CDIM * MLPD, b2 + l * CDIM, h, TOK, CDIM, MLPD);
  }
}

// Round 3
// 3588.834 us; speedup vs baseline: 1.0448x; 1.0448x over previous
//
#include <hip/hip_runtime.h>

#define DEPTHL 8
#define BZ 8
#define SEQ 1024
#define CDIM 768
#define HEADS 12
#define HDIM 64
#define MLPD 3072
#define TOK (BZ*SEQ)      // 8192
#define QKVN (3*CDIM)     // 2304

typedef __attribute__((ext_vector_type(8))) short vshort8;
typedef __attribute__((ext_vector_type(4))) short vshort4;
typedef __attribute__((ext_vector_type(4))) float vfloat4;

__device__ __forceinline__ short bf16_bits(float f) {
  union { float f; unsigned u; } x; x.f = f;
  unsigned r = (x.u + 0x7FFFu + ((x.u >> 16) & 1u)) >> 16;
  return (short)r;
}

#define GL16(g, l) __builtin_amdgcn_global_load_lds( \
    (const __attribute__((address_space(1))) unsigned int*)(g), \
    (__attribute__((address_space(3))) unsigned int*)(l), 16, 0, 0)

// ---------------- weight convert + transpose: fp32 [D][K][N] -> bf16 [D][N][K]
__global__ __launch_bounds__(256) void wconv_t(const float* __restrict__ in,
                                               short* __restrict__ out,
                                               int K, int N) {
  __shared__ float tile[32][33];
  const long d = blockIdx.z;
  in  += d * (long)K * N;
  out += d * (long)N * K;
  const int n0 = blockIdx.x * 32, k0 = blockIdx.y * 32;
  const int tx = threadIdx.x & 31, ty = threadIdx.x >> 5;
#pragma unroll
  for (int i = 0; i < 4; i++)
    tile[ty + 8*i][tx] = in[(long)(k0 + ty + 8*i) * N + n0 + tx];
  __syncthreads();
#pragma unroll
  for (int i = 0; i < 4; i++)
    out[(long)(n0 + ty + 8*i) * K + k0 + tx] = bf16_bits(tile[tx][ty + 8*i]);
}

// ---------------- V transpose per head: qkv V-part [tok][d] -> vt [bh][d][tok]
__global__ __launch_bounds__(256) void vtrans(const short* __restrict__ qkv,
                                              short* __restrict__ vt) {
  __shared__ short tile[32][34];
  const int bh = blockIdx.z;
  const int b = bh / HEADS, hh = bh % HEADS;
  const int t0 = blockIdx.x * 32, d0 = blockIdx.y * 32;
  const int tx = threadIdx.x & 31, ty = threadIdx.x >> 5;
  const short* src = qkv + ((long)b * SEQ + t0) * QKVN + 2 * CDIM + hh * HDIM + d0;
#pragma unroll
  for (int i = 0; i < 4; i++)
    tile[ty + 8*i][tx] = src[(long)(ty + 8*i) * QKVN + tx];
  __syncthreads();
  short* dst = vt + (long)bh * HDIM * SEQ + (long)d0 * SEQ + t0;
#pragma unroll
  for (int i = 0; i < 4; i++)
    dst[(long)(ty + 8*i) * SEQ + tx] = tile[tx][ty + 8*i];
}

// ---------------- LayerNorm: fp32 h row -> bf16 y row
__global__ __launch_bounds__(192) void ln_fwd(const float* __restrict__ h,
                                              const float* __restrict__ g,
                                              const float* __restrict__ be,
                                              short* __restrict__ y) {
  __shared__ float red[3];
  const int row = blockIdx.x;
  const int tid = threadIdx.x;
  const float4 v = ((const float4*)(h + (long)row * CDIM))[tid];
  float s = v.x + v.y + v.z + v.w;
#pragma unroll
  for (int m = 32; m >= 1; m >>= 1) s += __shfl_xor(s, m);
  if ((tid & 63) == 0) red[tid >> 6] = s;
  __syncthreads();
  const float mu = (red[0] + red[1] + red[2]) * (1.0f / CDIM);
  float dx = v.x - mu, dy = v.y - mu, dz = v.z - mu, dw = v.w - mu;
  float q = dx*dx + dy*dy + dz*dz + dw*dw;
  __syncthreads();
#pragma unroll
  for (int m = 32; m >= 1; m >>= 1) q += __shfl_xor(q, m);
  if ((tid & 63) == 0) red[tid >> 6] = q;
  __syncthreads();
  const float rstd = rsqrtf((red[0] + red[1] + red[2]) * (1.0f / CDIM) + 1e-5f);
  const float4 g4 = ((const float4*)g)[tid];
  const float4 b4 = ((const float4*)be)[tid];
  vshort4 o;
  o[0] = bf16_bits(dx * rstd * g4.x + b4.x);
  o[1] = bf16_bits(dy * rstd * g4.y + b4.y);
  o[2] = bf16_bits(dz * rstd * g4.z + b4.z);
  o[3] = bf16_bits(dw * rstd * g4.w + b4.w);
  *(vshort4*)(y + (long)row * CDIM + tid * 4) = o;
}

// ---------------- GEMM: C[M,N] = A[M,K] @ Bt[N,K]^T  (m97-style 128x128, BK=32)
template<int EPI>
__global__ __launch_bounds__(256) void gemm_bt(const short* __restrict__ A,
                                               const short* __restrict__ Bt,
                                               const float* __restrict__ bias,
                                               void* __restrict__ Cout,
                                               int M, int N, int K) {
  __shared__ short As[128 * 32];
  __shared__ short Bs[128 * 32];
  const int tid = threadIdx.x;
  const int wid = tid >> 6, lane = tid & 63;
  const int lg = lane >> 4, lr = lane & 15;
  const int wm = wid >> 1, wn = wid & 1;
  const long by = blockIdx.y;
  const long bx = blockIdx.x;

  vfloat4 acc[4][4];
#pragma unroll
  for (int i = 0; i < 4; i++)
#pragma unroll
    for (int j = 0; j < 4; j++) acc[i][j] = (vfloat4){0.f, 0.f, 0.f, 0.f};

  const int c = wid * 64 + lane;
  const short* Ag0 = A  + (by * 128 +      (c >> 2)) * (long)K + (c & 3) * 8;
  const short* Ag1 = A  + (by * 128 + 64 + (c >> 2)) * (long)K + (c & 3) * 8;
  const short* Bg0 = Bt + (bx * 128 +      (c >> 2)) * (long)K + (c & 3) * 8;
  const short* Bg1 = Bt + (bx * 128 + 64 + (c >> 2)) * (long)K + (c & 3) * 8;
  short* Al = As + c * 8;
  short* Bl = Bs + c * 8;

  for (int kk = 0; kk < K; kk += 32) {
    __syncthreads();
    GL16(Ag0 + kk, Al);
    GL16(Ag1 + kk, Al + 2048);
    GL16(Bg0 + kk, Bl);
    GL16(Bg1 + kk, Bl + 2048);
    __syncthreads();
    vshort8 a[4], b[4];
#pragma unroll
    for (int mt = 0; mt < 4; mt++)
      a[mt] = *(const vshort8*)(As + (wm * 64 + mt * 16 + lr) * 32 + lg * 8);
#pragma unroll
    for (int nt = 0; nt < 4; nt++)
      b[nt] = *(const vshort8*)(Bs + (wn * 64 + nt * 16 + lr) * 32 + lg * 8);
#pragma unroll
    for (int mt = 0; mt < 4; mt++)
#pragma unroll
      for (int nt = 0; nt < 4; nt++)
        acc[mt][nt] = __builtin_amdgcn_mfma_f32_16x16x32_bf16(a[mt], b[nt], acc[mt][nt], 0, 0, 0);
  }

  const long row0 = by * 128 + wm * 64;
  const long col0 = bx * 128 + wn * 64;
#pragma unroll
  for (int mt = 0; mt < 4; mt++) {
#pragma unroll
    for (int nt = 0; nt < 4; nt++) {
      const long col = col0 + nt * 16 + lr;
      float bv = 0.f;
      if (EPI != 0) bv = bias[col];
#pragma unroll
      for (int r = 0; r < 4; r++) {
        const long row = row0 + mt * 16 + lg * 4 + r;
        float v = acc[mt][nt][r];
        if (EPI == 0) {
          ((short*)Cout)[row * N + col] = bf16_bits(v);
        } else if (EPI == 1) {
          v += bv; v = v > 0.f ? v : 0.f;
          ((short*)Cout)[row * N + col] = bf16_bits(v);
        } else {
          float* hp = (float*)Cout + row * N + col;
          *hp = *hp + v + bv;
        }
      }
    }
  }
}

// ---------------- fused attention v2: swapped QK^T, in-register double softmax
// grid (SEQ/16, BZ*HEADS), 256 threads (4 waves). Wave w owns kv range [w*256, w*256+256).
__global__ __launch_bounds__(256) void attn_fused2(const short* __restrict__ qkv,
                                                   const short* __restrict__ vt,
                                                   short* __restrict__ o) {
  __shared__ short P_lds[16 * 1024];        // P[q][kv] bf16, byte ^= (q&7)<<4
  __shared__ float redm[4][16], redz[4][16], redt[4][16];
  const int qt = blockIdx.x, bh = blockIdx.y;
  const int b = bh / HEADS, hh = bh % HEADS;
  const int tid = threadIdx.x, wid = tid >> 6, lane = tid & 63;
  const int lg = lane >> 4, lr = lane & 15;
  const long tokbase = (long)b * SEQ;
  const short* qbase = qkv + tokbase * QKVN + hh * HDIM;
  const short* kbase = qbase + CDIM;
  const short* vtb = vt + (long)bh * HDIM * SEQ;

  // Q fragments (B-operand: lane lr = q row)
  vshort8 qf[2];
#pragma unroll
  for (int ks = 0; ks < 2; ks++)
    qf[ks] = *(const vshort8*)(qbase + (long)(qt * 16 + lr) * QKVN + ks * 32 + lg * 8);

  // ---- Phase 1: S^T = K @ Q^T for this wave's 16 kv-tiles; lane holds q=lr, kv=n0+lg*4+r
  vfloat4 s[16];
#pragma unroll
  for (int i = 0; i < 16; i++) {
    const int n0 = wid * 256 + i * 16;
    vfloat4 acc = (vfloat4){0.f, 0.f, 0.f, 0.f};
#pragma unroll
    for (int ks = 0; ks < 2; ks++) {
      vshort8 kf = *(const vshort8*)(kbase + (long)(n0 + lr) * QKVN + ks * 32 + lg * 8);
      acc = __builtin_amdgcn_mfma_f32_16x16x32_bf16(kf, qf[ks], acc, 0, 0, 0);
    }
    s[i][0] = acc[0] * 0.125f; s[i][1] = acc[1] * 0.125f;
    s[i][2] = acc[2] * 0.125f; s[i][3] = acc[3] * 0.125f;
  }

  // ---- Phase 2: double softmax, in registers + tiny cross-wave reduces
  // row max (per q = lr)
  vfloat4 mv = s[0];
#pragma unroll
  for (int i = 1; i < 16; i++) {
    mv[0] = fmaxf(mv[0], s[i][0]); mv[1] = fmaxf(mv[1], s[i][1]);
    mv[2] = fmaxf(mv[2], s[i][2]); mv[3] = fmaxf(mv[3], s[i][3]);
  }
  float m = fmaxf(fmaxf(mv[0], mv[1]), fmaxf(mv[2], mv[3]));
  m = fmaxf(m, __shfl_xor(m, 16));
  m = fmaxf(m, __shfl_xor(m, 32));
  if (lane < 16) redm[wid][lr] = m;
  __syncthreads();
  m = fmaxf(fmaxf(redm[0][lr], redm[1][lr]), fmaxf(redm[2][lr], redm[3][lr]));

  // z = sum exp(x-m)
  float z = 0.f;
#pragma unroll
  for (int i = 0; i < 16; i++) {
#pragma unroll
    for (int r = 0; r < 4; r++) { s[i][r] = __expf(s[i][r] - m); z += s[i][r]; }
  }
  z += __shfl_xor(z, 16);
  z += __shfl_xor(z, 32);
  if (lane < 16) redz[wid][lr] = z;
  __syncthreads();
  z = redz[0][lr] + redz[1][lr] + redz[2][lr] + redz[3][lr];
  const float rz = 1.0f / z;

  // second softmax: t2 = sum exp(p), p = e*rz  (p in [0,1], exp safe unshifted)
  float t2 = 0.f;
#pragma unroll
  for (int i = 0; i < 16; i++) {
#pragma unroll
    for (int r = 0; r < 4; r++) { s[i][r] = __expf(s[i][r] * rz); t2 += s[i][r]; }
  }
  t2 += __shfl_xor(t2, 16);
  t2 += __shfl_xor(t2, 32);
  if (lane < 16) redt[wid][lr] = t2;
  __syncthreads();
  t2 = redt[0][lr] + redt[1][lr] + redt[2][lr] + redt[3][lr];
  const float rt = 1.0f / t2;

  // ---- pack P -> LDS (b64 stores, swizzled; 4 consecutive kv per lane)
#pragma unroll
  for (int i = 0; i < 16; i++) {
    const int sbase = lr * 1024 + wid * 256 + i * 16 + lg * 4;   // shorts
    const int byt = (sbase * 2) ^ ((lr & 7) << 4);
    vshort4 pk;
    pk[0] = bf16_bits(s[i][0] * rt); pk[1] = bf16_bits(s[i][1] * rt);
    pk[2] = bf16_bits(s[i][2] * rt); pk[3] = bf16_bits(s[i][3] * rt);
    *(vshort4*)((char*)P_lds + byt) = pk;
  }
  __syncthreads();

  // ---- Phase 3: O[16q][16d] per wave (dt = wid), kv streamed from P_lds + global vt
  const int dt = wid;
  vfloat4 oacc = (vfloat4){0.f, 0.f, 0.f, 0.f};
  const short* vrow = vtb + (long)(dt * 16 + lr) * SEQ + lg * 8;
#pragma unroll 8
  for (int win = 0; win < 32; win++) {
    const int abyt = (lr * 2048 + win * 64 + lg * 16) ^ ((lr & 7) << 4);
    vshort8 af = *(const vshort8*)((char*)P_lds + abyt);
    vshort8 bfr = *(const vshort8*)(vrow + win * 32);
    oacc = __builtin_amdgcn_mfma_f32_16x16x32_bf16(af, bfr, oacc, 0, 0, 0);
  }

#pragma unroll
  for (int r = 0; r < 4; r++) {
    const long row = tokbase + qt * 16 + lg * 4 + r;
    o[row * CDIM + hh * HDIM + dt * 16 + lr] = bf16_bits(oacc[r]);
  }
}

extern "C" void kernel_launch(void* const* d_in, const int* in_sizes, int n_in,
                              void* d_out, int out_size, void* d_ws, size_t ws_size,
                              hipStream_t stream) {
  const float* x     = (const float*)d_in[0];
  const float* ln1_g = (const float*)d_in[1];
  const float* ln1_b = (const float*)d_in[2];
  const float* wqkv  = (const float*)d_in[3];
  const float* wproj = (const float*)d_in[4];
  const float* bproj = (const float*)d_in[5];
  const float* ln2_g = (const float*)d_in[6];
  const float* ln2_b = (const float*)d_in[7];
  const float* w1    = (const float*)d_in[8];
  const float* b1    = (const float*)d_in[9];
  const float* w2    = (const float*)d_in[10];
  const float* b2    = (const float*)d_in[11];
  float* h = (float*)d_out;

  char* ws = (char*)d_ws;
  short* wqkv_t  = (short*)ws; ws += (size_t)DEPTHL * QKVN * CDIM * 2;
  short* wproj_t = (short*)ws; ws += (size_t)DEPTHL * CDIM * CDIM * 2;
  short* w1_t    = (short*)ws; ws += (size_t)DEPTHL * MLPD * CDIM * 2;
  short* w2_t    = (short*)ws; ws += (size_t)DEPTHL * CDIM * MLPD * 2;
  short* ybf     = (short*)ws; ws += (size_t)TOK * CDIM * 2;
  short* qkvbf   = (short*)ws; ws += (size_t)TOK * QKVN * 2;
  short* obf     = (short*)ws; ws += (size_t)TOK * CDIM * 2;
  short* f1bf    = (short*)ws; ws += (size_t)TOK * MLPD * 2;
  short* vtb     = f1bf;   // overlay: vt lifetime [vtrans, attn] disjoint from f1 [fc1, fc2]

  hipMemcpyAsync(h, x, (size_t)TOK * CDIM * sizeof(float), hipMemcpyDeviceToDevice, stream);

  wconv_t<<<dim3(QKVN / 32, CDIM / 32, DEPTHL), 256, 0, stream>>>(wqkv, wqkv_t, CDIM, QKVN);
  wconv_t<<<dim3(CDIM / 32, CDIM / 32, DEPTHL), 256, 0, stream>>>(wproj, wproj_t, CDIM, CDIM);
  wconv_t<<<dim3(MLPD / 32, CDIM / 32, DEPTHL), 256, 0, stream>>>(w1, w1_t, CDIM, MLPD);
  wconv_t<<<dim3(CDIM / 32, MLPD / 32, DEPTHL), 256, 0, stream>>>(w2, w2_t, MLPD, CDIM);

  for (int l = 0; l < DEPTHL; l++) {
    ln_fwd<<<TOK, 192, 0, stream>>>(h, ln1_g + l * CDIM, ln1_b + l * CDIM, ybf);
    gemm_bt<0><<<dim3(QKVN / 128, TOK / 128), 256, 0, stream>>>(
        ybf, wqkv_t + (size_t)l * QKVN * CDIM, nullptr, qkvbf, TOK, QKVN, CDIM);
    vtrans<<<dim3(SEQ / 32, HDIM / 32, BZ * HEADS), 256, 0, stream>>>(qkvbf, vtb);
    attn_fused2<<<dim3(SEQ / 16, BZ * HEADS), 256, 0, stream>>>(qkvbf, vtb, obf);
    gemm_bt<2><<<dim3(CDIM / 128, TOK / 128), 256, 0, stream>>>(
        obf, wproj_t + (size_t)l * CDIM * CDIM, bproj + l * CDIM, h, TOK, CDIM, CDIM);
    ln_fwd<<<TOK, 192, 0, stream>>>(h, ln2_g + l * CDIM, ln2_b + l * CDIM, ybf);
    gemm_bt<1><<<dim3(MLPD / 128, TOK / 128), 256, 0, stream>>>(
        ybf, w1_t + (size_t)l * MLPD * CDIM, b1 + l * MLPD, f1bf, TOK, MLPD, CDIM);
    gemm_bt<2><<<dim3(CDIM / 128, TOK / 128), 256, 0, stream>>>(
        f1bf, w2_t + (size_t)l * CDIM * MLPD, b2 + l * CDIM, h, TOK, CDIM, MLPD);
  }
}

// Round 4
// 3509.891 us; speedup vs baseline: 1.0683x; 1.0225x over previous
//
#include <hip/hip_runtime.h>

#define DEPTHL 8
#define BZ 8
#define SEQ 1024
#define CDIM 768
#define HEADS 12
#define HDIM 64
#define MLPD 3072
#define TOK (BZ*SEQ)      // 8192
#define QKVN (3*CDIM)     // 2304

typedef __attribute__((ext_vector_type(8))) short vshort8;
typedef __attribute__((ext_vector_type(4))) short vshort4;
typedef __attribute__((ext_vector_type(4))) float vfloat4;

__device__ __forceinline__ short bf16_bits(float f) {
  union { float f; unsigned u; } x; x.f = f;
  unsigned r = (x.u + 0x7FFFu + ((x.u >> 16) & 1u)) >> 16;
  return (short)r;
}

#define GL16(g, l) __builtin_amdgcn_global_load_lds( \
    (const __attribute__((address_space(1))) unsigned int*)(g), \
    (__attribute__((address_space(3))) unsigned int*)(l), 16, 0, 0)

// ---------------- weight convert + transpose: fp32 [D][K][N] -> bf16 [D][N][K]
__global__ __launch_bounds__(256) void wconv_t(const float* __restrict__ in,
                                               short* __restrict__ out,
                                               int K, int N) {
  __shared__ float tile[32][33];
  const long d = blockIdx.z;
  in  += d * (long)K * N;
  out += d * (long)N * K;
  const int n0 = blockIdx.x * 32, k0 = blockIdx.y * 32;
  const int tx = threadIdx.x & 31, ty = threadIdx.x >> 5;
#pragma unroll
  for (int i = 0; i < 4; i++)
    tile[ty + 8*i][tx] = in[(long)(k0 + ty + 8*i) * N + n0 + tx];
  __syncthreads();
#pragma unroll
  for (int i = 0; i < 4; i++)
    out[(long)(n0 + ty + 8*i) * K + k0 + tx] = bf16_bits(tile[tx][ty + 8*i]);
}

// ---------------- V transpose per head: qkv V-part [tok][d] -> vt [bh][d][tok]
__global__ __launch_bounds__(256) void vtrans(const short* __restrict__ qkv,
                                              short* __restrict__ vt) {
  __shared__ short tile[32][34];
  const int bh = blockIdx.z;
  const int b = bh / HEADS, hh = bh % HEADS;
  const int t0 = blockIdx.x * 32, d0 = blockIdx.y * 32;
  const int tx = threadIdx.x & 31, ty = threadIdx.x >> 5;
  const short* src = qkv + ((long)b * SEQ + t0) * QKVN + 2 * CDIM + hh * HDIM + d0;
#pragma unroll
  for (int i = 0; i < 4; i++)
    tile[ty + 8*i][tx] = src[(long)(ty + 8*i) * QKVN + tx];
  __syncthreads();
  short* dst = vt + (long)bh * HDIM * SEQ + (long)d0 * SEQ + t0;
#pragma unroll
  for (int i = 0; i < 4; i++)
    dst[(long)(ty + 8*i) * SEQ + tx] = tile[tx][ty + 8*i];
}

// ---------------- LayerNorm: fp32 h row -> bf16 y row
__global__ __launch_bounds__(192) void ln_fwd(const float* __restrict__ h,
                                              const float* __restrict__ g,
                                              const float* __restrict__ be,
                                              short* __restrict__ y) {
  __shared__ float red[3];
  const int row = blockIdx.x;
  const int tid = threadIdx.x;
  const float4 v = ((const float4*)(h + (long)row * CDIM))[tid];
  float s = v.x + v.y + v.z + v.w;
#pragma unroll
  for (int m = 32; m >= 1; m >>= 1) s += __shfl_xor(s, m);
  if ((tid & 63) == 0) red[tid >> 6] = s;
  __syncthreads();
  const float mu = (red[0] + red[1] + red[2]) * (1.0f / CDIM);
  float dx = v.x - mu, dy = v.y - mu, dz = v.z - mu, dw = v.w - mu;
  float q = dx*dx + dy*dy + dz*dz + dw*dw;
  __syncthreads();
#pragma unroll
  for (int m = 32; m >= 1; m >>= 1) q += __shfl_xor(q, m);
  if ((tid & 63) == 0) red[tid >> 6] = q;
  __syncthreads();
  const float rstd = rsqrtf((red[0] + red[1] + red[2]) * (1.0f / CDIM) + 1e-5f);
  const float4 g4 = ((const float4*)g)[tid];
  const float4 b4 = ((const float4*)be)[tid];
  vshort4 o;
  o[0] = bf16_bits(dx * rstd * g4.x + b4.x);
  o[1] = bf16_bits(dy * rstd * g4.y + b4.y);
  o[2] = bf16_bits(dz * rstd * g4.z + b4.z);
  o[3] = bf16_bits(dw * rstd * g4.w + b4.w);
  *(vshort4*)(y + (long)row * CDIM + tid * 4) = o;
}

// ---------------- GEMM: C[M,N] = A[M,K] @ Bt[N,K]^T  (m97-style 128x128, BK=32)
// + m204 bijective XCD swizzle (all grids have nwg % 8 == 0)
template<int EPI>
__global__ __launch_bounds__(256) void gemm_bt(const short* __restrict__ A,
                                               const short* __restrict__ Bt,
                                               const float* __restrict__ bias,
                                               void* __restrict__ Cout,
                                               int M, int N, int K) {
  __shared__ short As[128 * 32];
  __shared__ short Bs[128 * 32];
  const int tid = threadIdx.x;
  const int wid = tid >> 6, lane = tid & 63;
  const int lg = lane >> 4, lr = lane & 15;
  const int wm = wid >> 1, wn = wid & 1;

  const int gx = gridDim.x;
  const int nwg = gx * gridDim.y;
  int flat = blockIdx.y * gx + blockIdx.x;
  flat = (flat & 7) * (nwg >> 3) + (flat >> 3);   // same-XCD blocks contiguous
  const long bx = flat % gx;
  const long by = flat / gx;

  vfloat4 acc[4][4];
#pragma unroll
  for (int i = 0; i < 4; i++)
#pragma unroll
    for (int j = 0; j < 4; j++) acc[i][j] = (vfloat4){0.f, 0.f, 0.f, 0.f};

  const int c = wid * 64 + lane;
  const short* Ag0 = A  + (by * 128 +      (c >> 2)) * (long)K + (c & 3) * 8;
  const short* Ag1 = A  + (by * 128 + 64 + (c >> 2)) * (long)K + (c & 3) * 8;
  const short* Bg0 = Bt + (bx * 128 +      (c >> 2)) * (long)K + (c & 3) * 8;
  const short* Bg1 = Bt + (bx * 128 + 64 + (c >> 2)) * (long)K + (c & 3) * 8;
  short* Al = As + c * 8;
  short* Bl = Bs + c * 8;

  for (int kk = 0; kk < K; kk += 32) {
    __syncthreads();
    GL16(Ag0 + kk, Al);
    GL16(Ag1 + kk, Al + 2048);
    GL16(Bg0 + kk, Bl);
    GL16(Bg1 + kk, Bl + 2048);
    __syncthreads();
    vshort8 a[4], b[4];
#pragma unroll
    for (int mt = 0; mt < 4; mt++)
      a[mt] = *(const vshort8*)(As + (wm * 64 + mt * 16 + lr) * 32 + lg * 8);
#pragma unroll
    for (int nt = 0; nt < 4; nt++)
      b[nt] = *(const vshort8*)(Bs + (wn * 64 + nt * 16 + lr) * 32 + lg * 8);
#pragma unroll
    for (int mt = 0; mt < 4; mt++)
#pragma unroll
      for (int nt = 0; nt < 4; nt++)
        acc[mt][nt] = __builtin_amdgcn_mfma_f32_16x16x32_bf16(a[mt], b[nt], acc[mt][nt], 0, 0, 0);
  }

  const long row0 = by * 128 + wm * 64;
  const long col0 = bx * 128 + wn * 64;
#pragma unroll
  for (int mt = 0; mt < 4; mt++) {
#pragma unroll
    for (int nt = 0; nt < 4; nt++) {
      const long col = col0 + nt * 16 + lr;
      float bv = 0.f;
      if (EPI != 0) bv = bias[col];
#pragma unroll
      for (int r = 0; r < 4; r++) {
        const long row = row0 + mt * 16 + lg * 4 + r;
        float v = acc[mt][nt][r];
        if (EPI == 0) {
          ((short*)Cout)[row * N + col] = bf16_bits(v);
        } else if (EPI == 1) {
          v += bv; v = v > 0.f ? v : 0.f;
          ((short*)Cout)[row * N + col] = bf16_bits(v);
        } else {
          float* hp = (float*)Cout + row * N + col;
          *hp = *hp + v + bv;
        }
      }
    }
  }
}

// ---------------- fused attention v3: XCD-local heads + deep load batching
// grid (SEQ/16=64, BZ*HEADS=96) remapped so each XCD owns 12 heads (K/V 3MB -> L2-resident)
__global__ __launch_bounds__(256, 2) void attn_fused3(const short* __restrict__ qkv,
                                                      const short* __restrict__ vt,
                                                      short* __restrict__ o) {
  __shared__ short P_lds[16 * 1024];        // P[q][kv] bf16, byte ^= (q&7)<<4
  __shared__ float redm[4][16], redz[4][16], redt[4][16];
  int flat = blockIdx.y * 64 + blockIdx.x;          // nwg = 6144
  flat = (flat & 7) * (6144 >> 3) + (flat >> 3);    // same-XCD: 768 contiguous = 12 heads
  const int qt = flat & 63;
  const int bh = flat >> 6;
  const int b = bh / HEADS, hh = bh % HEADS;
  const int tid = threadIdx.x, wid = tid >> 6, lane = tid & 63;
  const int lg = lane >> 4, lr = lane & 15;
  const long tokbase = (long)b * SEQ;
  const short* qbase = qkv + tokbase * QKVN + hh * HDIM;
  const short* kbase = qkv + tokbase * QKVN + CDIM + hh * HDIM;
  const short* vtb = vt + (long)bh * HDIM * SEQ;

  // Q fragments (B-operand: lane lr = q row)
  vshort8 qf[2];
#pragma unroll
  for (int ks = 0; ks < 2; ks++)
    qf[ks] = *(const vshort8*)(qbase + (long)(qt * 16 + lr) * QKVN + ks * 32 + lg * 8);

  // ---- Phase 1: S^T = K @ Q^T; 8-deep load batches (4 kv-tiles x 2 ks per batch)
  vfloat4 s[16];
#pragma unroll
  for (int bb = 0; bb < 4; bb++) {
    vshort8 kf[8];
#pragma unroll
    for (int u = 0; u < 4; u++) {
      const int n0 = wid * 256 + (bb * 4 + u) * 16;
#pragma unroll
      for (int ks = 0; ks < 2; ks++)
        kf[u * 2 + ks] = *(const vshort8*)(kbase + (long)(n0 + lr) * QKVN + ks * 32 + lg * 8);
    }
#pragma unroll
    for (int u = 0; u < 4; u++) {
      vfloat4 acc = (vfloat4){0.f, 0.f, 0.f, 0.f};
      acc = __builtin_amdgcn_mfma_f32_16x16x32_bf16(kf[u * 2 + 0], qf[0], acc, 0, 0, 0);
      acc = __builtin_amdgcn_mfma_f32_16x16x32_bf16(kf[u * 2 + 1], qf[1], acc, 0, 0, 0);
      const int i = bb * 4 + u;
      s[i][0] = acc[0] * 0.125f; s[i][1] = acc[1] * 0.125f;
      s[i][2] = acc[2] * 0.125f; s[i][3] = acc[3] * 0.125f;
    }
  }

  // ---- Phase 2: double softmax in registers + tiny cross-wave reduces
  vfloat4 mv = s[0];
#pragma unroll
  for (int i = 1; i < 16; i++) {
    mv[0] = fmaxf(mv[0], s[i][0]); mv[1] = fmaxf(mv[1], s[i][1]);
    mv[2] = fmaxf(mv[2], s[i][2]); mv[3] = fmaxf(mv[3], s[i][3]);
  }
  float m = fmaxf(fmaxf(mv[0], mv[1]), fmaxf(mv[2], mv[3]));
  m = fmaxf(m, __shfl_xor(m, 16));
  m = fmaxf(m, __shfl_xor(m, 32));
  if (lane < 16) redm[wid][lr] = m;
  __syncthreads();
  m = fmaxf(fmaxf(redm[0][lr], redm[1][lr]), fmaxf(redm[2][lr], redm[3][lr]));

  float z = 0.f;
#pragma unroll
  for (int i = 0; i < 16; i++) {
#pragma unroll
    for (int r = 0; r < 4; r++) { s[i][r] = __expf(s[i][r] - m); z += s[i][r]; }
  }
  z += __shfl_xor(z, 16);
  z += __shfl_xor(z, 32);
  if (lane < 16) redz[wid][lr] = z;
  __syncthreads();
  z = redz[0][lr] + redz[1][lr] + redz[2][lr] + redz[3][lr];
  const float rz = 1.0f / z;

  float t2 = 0.f;
#pragma unroll
  for (int i = 0; i < 16; i++) {
#pragma unroll
    for (int r = 0; r < 4; r++) { s[i][r] = __expf(s[i][r] * rz); t2 += s[i][r]; }
  }
  t2 += __shfl_xor(t2, 16);
  t2 += __shfl_xor(t2, 32);
  if (lane < 16) redt[wid][lr] = t2;
  __syncthreads();
  t2 = redt[0][lr] + redt[1][lr] + redt[2][lr] + redt[3][lr];
  const float rt = 1.0f / t2;

  // ---- pack P -> LDS (b64 stores, swizzled)
#pragma unroll
  for (int i = 0; i < 16; i++) {
    const int sbase = lr * 1024 + wid * 256 + i * 16 + lg * 4;
    const int byt = (sbase * 2) ^ ((lr & 7) << 4);
    vshort4 pk;
    pk[0] = bf16_bits(s[i][0] * rt); pk[1] = bf16_bits(s[i][1] * rt);
    pk[2] = bf16_bits(s[i][2] * rt); pk[3] = bf16_bits(s[i][3] * rt);
    *(vshort4*)((char*)P_lds + byt) = pk;
  }
  __syncthreads();

  // ---- Phase 3: O[16q][16d] per wave (dt = wid); 4-deep P/V batches
  const int dt = wid;
  vfloat4 oacc = (vfloat4){0.f, 0.f, 0.f, 0.f};
  const short* vrow = vtb + (long)(dt * 16 + lr) * SEQ + lg * 8;
#pragma unroll
  for (int bb = 0; bb < 8; bb++) {
    vshort8 ab[4], vb[4];
#pragma unroll
    for (int u = 0; u < 4; u++) {
      const int win = bb * 4 + u;
      const int abyt = (lr * 2048 + win * 64 + lg * 16) ^ ((lr & 7) << 4);
      ab[u] = *(const vshort8*)((char*)P_lds + abyt);
      vb[u] = *(const vshort8*)(vrow + win * 32);
    }
#pragma unroll
    for (int u = 0; u < 4; u++)
      oacc = __builtin_amdgcn_mfma_f32_16x16x32_bf16(ab[u], vb[u], oacc, 0, 0, 0);
  }

#pragma unroll
  for (int r = 0; r < 4; r++) {
    const long row = tokbase + qt * 16 + lg * 4 + r;
    o[row * CDIM + hh * HDIM + dt * 16 + lr] = bf16_bits(oacc[r]);
  }
}

extern "C" void kernel_launch(void* const* d_in, const int* in_sizes, int n_in,
                              void* d_out, int out_size, void* d_ws, size_t ws_size,
                              hipStream_t stream) {
  const float* x     = (const float*)d_in[0];
  const float* ln1_g = (const float*)d_in[1];
  const float* ln1_b = (const float*)d_in[2];
  const float* wqkv  = (const float*)d_in[3];
  const float* wproj = (const float*)d_in[4];
  const float* bproj = (const float*)d_in[5];
  const float* ln2_g = (const float*)d_in[6];
  const float* ln2_b = (const float*)d_in[7];
  const float* w1    = (const float*)d_in[8];
  const float* b1    = (const float*)d_in[9];
  const float* w2    = (const float*)d_in[10];
  const float* b2    = (const float*)d_in[11];
  float* h = (float*)d_out;

  char* ws = (char*)d_ws;
  short* wqkv_t  = (short*)ws; ws += (size_t)DEPTHL * QKVN * CDIM * 2;
  short* wproj_t = (short*)ws; ws += (size_t)DEPTHL * CDIM * CDIM * 2;
  short* w1_t    = (short*)ws; ws += (size_t)DEPTHL * MLPD * CDIM * 2;
  short* w2_t    = (short*)ws; ws += (size_t)DEPTHL * CDIM * MLPD * 2;
  short* ybf     = (short*)ws; ws += (size_t)TOK * CDIM * 2;
  short* qkvbf   = (short*)ws; ws += (size_t)TOK * QKVN * 2;
  short* obf     = (short*)ws; ws += (size_t)TOK * CDIM * 2;
  short* f1bf    = (short*)ws; ws += (size_t)TOK * MLPD * 2;
  short* vtb     = f1bf;   // overlay: vt lifetime [vtrans, attn] disjoint from f1 [fc1, fc2]

  hipMemcpyAsync(h, x, (size_t)TOK * CDIM * sizeof(float), hipMemcpyDeviceToDevice, stream);

  wconv_t<<<dim3(QKVN / 32, CDIM / 32, DEPTHL), 256, 0, stream>>>(wqkv, wqkv_t, CDIM, QKVN);
  wconv_t<<<dim3(CDIM / 32, CDIM / 32, DEPTHL), 256, 0, stream>>>(wproj, wproj_t, CDIM, CDIM);
  wconv_t<<<dim3(MLPD / 32, CDIM / 32, DEPTHL), 256, 0, stream>>>(w1, w1_t, CDIM, MLPD);
  wconv_t<<<dim3(CDIM / 32, MLPD / 32, DEPTHL), 256, 0, stream>>>(w2, w2_t, MLPD, CDIM);

  for (int l = 0; l < DEPTHL; l++) {
    ln_fwd<<<TOK, 192, 0, stream>>>(h, ln1_g + l * CDIM, ln1_b + l * CDIM, ybf);
    gemm_bt<0><<<dim3(QKVN / 128, TOK / 128), 256, 0, stream>>>(
        ybf, wqkv_t + (size_t)l * QKVN * CDIM, nullptr, qkvbf, TOK, QKVN, CDIM);
    vtrans<<<dim3(SEQ / 32, HDIM / 32, BZ * HEADS), 256, 0, stream>>>(qkvbf, vtb);
    attn_fused3<<<dim3(SEQ / 16, BZ * HEADS), 256, 0, stream>>>(qkvbf, vtb, obf);
    gemm_bt<2><<<dim3(CDIM / 128, TOK / 128), 256, 0, stream>>>(
        obf, wproj_t + (size_t)l * CDIM * CDIM, bproj + l * CDIM, h, TOK, CDIM, CDIM);
    ln_fwd<<<TOK, 192, 0, stream>>>(h, ln2_g + l * CDIM, ln2_b + l * CDIM, ybf);
    gemm_bt<1><<<dim3(MLPD / 128, TOK / 128), 256, 0, stream>>>(
        ybf, w1_t + (size_t)l * MLPD * CDIM, b1 + l * MLPD, f1bf, TOK, MLPD, CDIM);
    gemm_bt<2><<<dim3(CDIM / 128, TOK / 128), 256, 0, stream>>>(
        f1bf, w2_t + (size_t)l * CDIM * MLPD, b2 + l * CDIM, h, TOK, CDIM, MLPD);
  }
}

// Round 6
// 3507.618 us; speedup vs baseline: 1.0690x; 1.0006x over previous
//
#include <hip/hip_runtime.h>
#include <hip/hip_bf16.h>

#define DEPTHL 8
#define BZ 8
#define SEQ 1024
#define CDIM 768
#define HEADS 12
#define HDIM 64
#define MLPD 3072
#define TOK (BZ*SEQ)      // 8192
#define QKVN (3*CDIM)     // 2304

typedef __attribute__((ext_vector_type(8))) short vshort8;
typedef __attribute__((ext_vector_type(4))) short vshort4;
typedef __attribute__((ext_vector_type(4))) float vfloat4;

__device__ __forceinline__ short bf16_bits(float f) {
  union { float f; unsigned u; } x; x.f = f;
  unsigned r = (x.u + 0x7FFFu + ((x.u >> 16) & 1u)) >> 16;
  return (short)r;
}

__device__ __forceinline__ unsigned pk_bf16(float a, float b) {
  unsigned r;
  asm("v_cvt_pk_bf16_f32 %0, %1, %2" : "=v"(r) : "v"(a), "v"(b));
  return r;   // low16 = bf16(a), high16 = bf16(b)
}

#define GL16(g, l) __builtin_amdgcn_global_load_lds( \
    (const __attribute__((address_space(1))) unsigned int*)(g), \
    (__attribute__((address_space(3))) unsigned int*)(l), 16, 0, 0)

// ---------------- weight convert + transpose: fp32 [D][K][N] -> bf16 [D][N][K]
__global__ __launch_bounds__(256) void wconv_t(const float* __restrict__ in,
                                               short* __restrict__ out,
                                               int K, int N) {
  __shared__ float tile[32][33];
  const long d = blockIdx.z;
  in  += d * (long)K * N;
  out += d * (long)N * K;
  const int n0 = blockIdx.x * 32, k0 = blockIdx.y * 32;
  const int tx = threadIdx.x & 31, ty = threadIdx.x >> 5;
#pragma unroll
  for (int i = 0; i < 4; i++)
    tile[ty + 8*i][tx] = in[(long)(k0 + ty + 8*i) * N + n0 + tx];
  __syncthreads();
#pragma unroll
  for (int i = 0; i < 4; i++)
    out[(long)(n0 + ty + 8*i) * K + k0 + tx] = bf16_bits(tile[tx][ty + 8*i]);
}

// ---------------- V transpose per head: qkv V-part [tok][d] -> vt [bh][d][tok]
__global__ __launch_bounds__(256) void vtrans(const short* __restrict__ qkv,
                                              short* __restrict__ vt) {
  __shared__ short tile[32][34];
  const int bh = blockIdx.z;
  const int b = bh / HEADS, hh = bh % HEADS;
  const int t0 = blockIdx.x * 32, d0 = blockIdx.y * 32;
  const int tx = threadIdx.x & 31, ty = threadIdx.x >> 5;
  const short* src = qkv + ((long)b * SEQ + t0) * QKVN + 2 * CDIM + hh * HDIM + d0;
#pragma unroll
  for (int i = 0; i < 4; i++)
    tile[ty + 8*i][tx] = src[(long)(ty + 8*i) * QKVN + tx];
  __syncthreads();
  short* dst = vt + (long)bh * HDIM * SEQ + (long)d0 * SEQ + t0;
#pragma unroll
  for (int i = 0; i < 4; i++)
    dst[(long)(ty + 8*i) * SEQ + tx] = tile[tx][ty + 8*i];
}

// ---------------- LayerNorm: fp32 h row -> bf16 y row
__global__ __launch_bounds__(192) void ln_fwd(const float* __restrict__ h,
                                              const float* __restrict__ g,
                                              const float* __restrict__ be,
                                              short* __restrict__ y) {
  __shared__ float red[3];
  const int row = blockIdx.x;
  const int tid = threadIdx.x;
  const float4 v = ((const float4*)(h + (long)row * CDIM))[tid];
  float s = v.x + v.y + v.z + v.w;
#pragma unroll
  for (int m = 32; m >= 1; m >>= 1) s += __shfl_xor(s, m);
  if ((tid & 63) == 0) red[tid >> 6] = s;
  __syncthreads();
  const float mu = (red[0] + red[1] + red[2]) * (1.0f / CDIM);
  float dx = v.x - mu, dy = v.y - mu, dz = v.z - mu, dw = v.w - mu;
  float q = dx*dx + dy*dy + dz*dz + dw*dw;
  __syncthreads();
#pragma unroll
  for (int m = 32; m >= 1; m >>= 1) q += __shfl_xor(q, m);
  if ((tid & 63) == 0) red[tid >> 6] = q;
  __syncthreads();
  const float rstd = rsqrtf((red[0] + red[1] + red[2]) * (1.0f / CDIM) + 1e-5f);
  const float4 g4 = ((const float4*)g)[tid];
  const float4 b4 = ((const float4*)be)[tid];
  vshort4 o;
  o[0] = bf16_bits(dx * rstd * g4.x + b4.x);
  o[1] = bf16_bits(dy * rstd * g4.y + b4.y);
  o[2] = bf16_bits(dz * rstd * g4.z + b4.z);
  o[3] = bf16_bits(dw * rstd * g4.w + b4.w);
  *(vshort4*)(y + (long)row * CDIM + tid * 4) = o;
}

// ---------------- GEMM: C[M,N] = A[M,K] @ Bt[N,K]^T  (m97-style 128x128, BK=32)
// + m204 bijective XCD swizzle (all grids have nwg % 8 == 0)
template<int EPI>
__global__ __launch_bounds__(256) void gemm_bt(const short* __restrict__ A,
                                               const short* __restrict__ Bt,
                                               const float* __restrict__ bias,
                                               void* __restrict__ Cout,
                                               int M, int N, int K) {
  __shared__ short As[128 * 32];
  __shared__ short Bs[128 * 32];
  const int tid = threadIdx.x;
  const int wid = tid >> 6, lane = tid & 63;
  const int lg = lane >> 4, lr = lane & 15;
  const int wm = wid >> 1, wn = wid & 1;

  const int gx = gridDim.x;
  const int nwg = gx * gridDim.y;
  int flat = blockIdx.y * gx + blockIdx.x;
  flat = (flat & 7) * (nwg >> 3) + (flat >> 3);   // same-XCD blocks contiguous
  const long bx = flat % gx;
  const long by = flat / gx;

  vfloat4 acc[4][4];
#pragma unroll
  for (int i = 0; i < 4; i++)
#pragma unroll
    for (int j = 0; j < 4; j++) acc[i][j] = (vfloat4){0.f, 0.f, 0.f, 0.f};

  const int c = wid * 64 + lane;
  const short* Ag0 = A  + (by * 128 +      (c >> 2)) * (long)K + (c & 3) * 8;
  const short* Ag1 = A  + (by * 128 + 64 + (c >> 2)) * (long)K + (c & 3) * 8;
  const short* Bg0 = Bt + (bx * 128 +      (c >> 2)) * (long)K + (c & 3) * 8;
  const short* Bg1 = Bt + (bx * 128 + 64 + (c >> 2)) * (long)K + (c & 3) * 8;
  short* Al = As + c * 8;
  short* Bl = Bs + c * 8;

  for (int kk = 0; kk < K; kk += 32) {
    __syncthreads();
    GL16(Ag0 + kk, Al);
    GL16(Ag1 + kk, Al + 2048);
    GL16(Bg0 + kk, Bl);
    GL16(Bg1 + kk, Bl + 2048);
    __syncthreads();
    vshort8 a[4], b[4];
#pragma unroll
    for (int mt = 0; mt < 4; mt++)
      a[mt] = *(const vshort8*)(As + (wm * 64 + mt * 16 + lr) * 32 + lg * 8);
#pragma unroll
    for (int nt = 0; nt < 4; nt++)
      b[nt] = *(const vshort8*)(Bs + (wn * 64 + nt * 16 + lr) * 32 + lg * 8);
#pragma unroll
    for (int mt = 0; mt < 4; mt++)
#pragma unroll
      for (int nt = 0; nt < 4; nt++)
        acc[mt][nt] = __builtin_amdgcn_mfma_f32_16x16x32_bf16(a[mt], b[nt], acc[mt][nt], 0, 0, 0);
  }

  const long row0 = by * 128 + wm * 64;
  const long col0 = bx * 128 + wn * 64;
#pragma unroll
  for (int mt = 0; mt < 4; mt++) {
#pragma unroll
    for (int nt = 0; nt < 4; nt++) {
      const long col = col0 + nt * 16 + lr;
      float bv = 0.f;
      if (EPI != 0) bv = bias[col];
#pragma unroll
      for (int r = 0; r < 4; r++) {
        const long row = row0 + mt * 16 + lg * 4 + r;
        float v = acc[mt][nt][r];
        if (EPI == 0) {
          ((short*)Cout)[row * N + col] = bf16_bits(v);
        } else if (EPI == 1) {
          v += bv; v = v > 0.f ? v : 0.f;
          ((short*)Cout)[row * N + col] = bf16_bits(v);
        } else {
          float* hp = (float*)Cout + row * N + col;
          *hp = *hp + v + bv;
        }
      }
    }
  }
}

// ---------------- fused attention v4: per-wave P_lds, kv-split PV, O block-reduce
// grid (SEQ/16=64, BZ*HEADS=96) remapped so each XCD owns 12 heads.
// Wave w: kv range [w*256, w*256+256). Softmax row split across waves (3 reduces).
__global__ __launch_bounds__(256, 4) void attn_fused4(const short* __restrict__ qkv,
                                                      const short* __restrict__ vt,
                                                      short* __restrict__ o) {
  __shared__ __align__(16) short P_lds[4 * 4096];   // per-wave 16q x 256kv bf16 (8KB each)
  __shared__ float redm[4][16], redz[4][16], redt[4][16];
  int flat = blockIdx.y * 64 + blockIdx.x;          // nwg = 6144
  flat = (flat & 7) * (6144 >> 3) + (flat >> 3);    // same-XCD: 768 contiguous = 12 heads
  const int qt = flat & 63;
  const int bh = flat >> 6;
  const int b = bh / HEADS, hh = bh % HEADS;
  const int tid = threadIdx.x, wid = tid >> 6, lane = tid & 63;
  const int lg = lane >> 4, lr = lane & 15;
  const long tokbase = (long)b * SEQ;
  const short* qbase = qkv + tokbase * QKVN + hh * HDIM;
  const short* kbase = qkv + tokbase * QKVN + CDIM + hh * HDIM;
  const short* vtb = vt + (long)bh * HDIM * SEQ;
  char* Pw = (char*)P_lds + wid * 8192;

  // Q fragments (B-operand: lane lr = q row)
  vshort8 qf[2];
#pragma unroll
  for (int ks = 0; ks < 2; ks++)
    qf[ks] = *(const vshort8*)(qbase + (long)(qt * 16 + lr) * QKVN + ks * 32 + lg * 8);

  // ---- Phase 1: S^T = K @ Q^T (raw, unscaled); lane holds q=lr, kv=wid*256+i*16+lg*4+r
  vfloat4 s[16];
#pragma unroll
  for (int bb = 0; bb < 4; bb++) {
    vshort8 kf[8];
#pragma unroll
    for (int u = 0; u < 4; u++) {
      const int n0 = wid * 256 + (bb * 4 + u) * 16;
#pragma unroll
      for (int ks = 0; ks < 2; ks++)
        kf[u * 2 + ks] = *(const vshort8*)(kbase + (long)(n0 + lr) * QKVN + ks * 32 + lg * 8);
    }
#pragma unroll
    for (int u = 0; u < 4; u++) {
      vfloat4 acc = (vfloat4){0.f, 0.f, 0.f, 0.f};
      acc = __builtin_amdgcn_mfma_f32_16x16x32_bf16(kf[u * 2 + 0], qf[0], acc, 0, 0, 0);
      acc = __builtin_amdgcn_mfma_f32_16x16x32_bf16(kf[u * 2 + 1], qf[1], acc, 0, 0, 0);
      s[bb * 4 + u] = acc;
    }
  }

  // ---- Phase 2: double softmax (scale folded into exp arg via fma; tree reductions)
  float mt16[16];
#pragma unroll
  for (int i = 0; i < 16; i++)
    mt16[i] = fmaxf(fmaxf(s[i][0], s[i][1]), fmaxf(s[i][2], s[i][3]));
#pragma unroll
  for (int st = 8; st >= 1; st >>= 1)
#pragma unroll
    for (int i = 0; i < 8; i++) if (i < st) mt16[i] = fmaxf(mt16[i], mt16[i + st]);
  float m = mt16[0];
  m = fmaxf(m, __shfl_xor(m, 16));
  m = fmaxf(m, __shfl_xor(m, 32));
  if (lane < 16) redm[wid][lr] = m;
  __syncthreads();
  m = fmaxf(fmaxf(redm[0][lr], redm[1][lr]), fmaxf(redm[2][lr], redm[3][lr]));
  const float msc = m * 0.125f;

  float zt[16];
#pragma unroll
  for (int i = 0; i < 16; i++) {
    float e0 = __expf(fmaf(s[i][0], 0.125f, -msc));
    float e1 = __expf(fmaf(s[i][1], 0.125f, -msc));
    float e2 = __expf(fmaf(s[i][2], 0.125f, -msc));
    float e3 = __expf(fmaf(s[i][3], 0.125f, -msc));
    s[i][0] = e0; s[i][1] = e1; s[i][2] = e2; s[i][3] = e3;
    zt[i] = (e0 + e1) + (e2 + e3);
  }
#pragma unroll
  for (int st = 8; st >= 1; st >>= 1)
#pragma unroll
    for (int i = 0; i < 8; i++) if (i < st) zt[i] += zt[i + st];
  float z = zt[0];
  z += __shfl_xor(z, 16);
  z += __shfl_xor(z, 32);
  if (lane < 16) redz[wid][lr] = z;
  __syncthreads();
  z = (redz[0][lr] + redz[1][lr]) + (redz[2][lr] + redz[3][lr]);
  const float rz = 1.0f / z;

  float tt[16];
#pragma unroll
  for (int i = 0; i < 16; i++) {
    float p0 = __expf(s[i][0] * rz);
    float p1 = __expf(s[i][1] * rz);
    float p2 = __expf(s[i][2] * rz);
    float p3 = __expf(s[i][3] * rz);
    s[i][0] = p0; s[i][1] = p1; s[i][2] = p2; s[i][3] = p3;
    tt[i] = (p0 + p1) + (p2 + p3);
  }
#pragma unroll
  for (int st = 8; st >= 1; st >>= 1)
#pragma unroll
    for (int i = 0; i < 8; i++) if (i < st) tt[i] += tt[i + st];
  float t2 = tt[0];
  t2 += __shfl_xor(t2, 16);
  t2 += __shfl_xor(t2, 32);
  if (lane < 16) redt[wid][lr] = t2;
  __syncthreads();
  t2 = (redt[0][lr] + redt[1][lr]) + (redt[2][lr] + redt[3][lr]);
  const float rt = 1.0f / t2;

  // ---- pack P -> per-wave LDS region (hw cvt_pk; no block barrier needed)
#pragma unroll
  for (int i = 0; i < 16; i++) {
    const int byt = (lr * 512 + i * 32 + lg * 8) ^ ((lr & 7) << 4);
    uint2 pk;
    pk.x = pk_bf16(s[i][0] * rt, s[i][1] * rt);
    pk.y = pk_bf16(s[i][2] * rt, s[i][3] * rt);
    *(uint2*)(Pw + byt) = pk;
  }

  // ---- Phase 3: partial O over this wave's kv range, ALL 64 d (4 d-tiles)
  vfloat4 oacc[4];
#pragma unroll
  for (int dt = 0; dt < 4; dt++) oacc[dt] = (vfloat4){0.f, 0.f, 0.f, 0.f};
#pragma unroll
  for (int j = 0; j < 8; j++) {
    const int abyt = (lr * 512 + j * 64 + lg * 16) ^ ((lr & 7) << 4);
    vshort8 af = *(const vshort8*)(Pw + abyt);
#pragma unroll
    for (int dt = 0; dt < 4; dt++) {
      vshort8 vb = *(const vshort8*)(vtb + (long)(dt * 16 + lr) * SEQ + wid * 256 + j * 32 + lg * 8);
      oacc[dt] = __builtin_amdgcn_mfma_f32_16x16x32_bf16(af, vb, oacc[dt], 0, 0, 0);
    }
  }

  // ---- O block-reduce: partials into own P region (fp32 [16q][64d]), then sum
#pragma unroll
  for (int dt = 0; dt < 4; dt++)
#pragma unroll
    for (int r = 0; r < 4; r++)
      *(float*)(Pw + ((lg * 4 + r) * 64 + dt * 16 + lr) * 4) = oacc[dt][r];
  __syncthreads();

  const int q = tid >> 4, d0 = (tid & 15) * 4;
  float4 a0 = *(const float4*)((const char*)P_lds + 0 * 8192 + (q * 64 + d0) * 4);
  float4 a1 = *(const float4*)((const char*)P_lds + 1 * 8192 + (q * 64 + d0) * 4);
  float4 a2 = *(const float4*)((const char*)P_lds + 2 * 8192 + (q * 64 + d0) * 4);
  float4 a3 = *(const float4*)((const char*)P_lds + 3 * 8192 + (q * 64 + d0) * 4);
  float ox = (a0.x + a1.x) + (a2.x + a3.x);
  float oy = (a0.y + a1.y) + (a2.y + a3.y);
  float oz = (a0.z + a1.z) + (a2.z + a3.z);
  float ow = (a0.w + a1.w) + (a2.w + a3.w);
  uint2 ob;
  ob.x = pk_bf16(ox, oy);
  ob.y = pk_bf16(oz, ow);
  *(uint2*)(o + (tokbase + qt * 16 + q) * CDIM + hh * HDIM + d0) = ob;
}

extern "C" void kernel_launch(void* const* d_in, const int* in_sizes, int n_in,
                              void* d_out, int out_size, void* d_ws, size_t ws_size,
                              hipStream_t stream) {
  const float* x     = (const float*)d_in[0];
  const float* ln1_g = (const float*)d_in[1];
  const float* ln1_b = (const float*)d_in[2];
  const float* wqkv  = (const float*)d_in[3];
  const float* wproj = (const float*)d_in[4];
  const float* bproj = (const float*)d_in[5];
  const float* ln2_g = (const float*)d_in[6];
  const float* ln2_b = (const float*)d_in[7];
  const float* w1    = (const float*)d_in[8];
  const float* b1    = (const float*)d_in[9];
  const float* w2    = (const float*)d_in[10];
  const float* b2    = (const float*)d_in[11];
  float* h = (float*)d_out;

  char* ws = (char*)d_ws;
  short* wqkv_t  = (short*)ws; ws += (size_t)DEPTHL * QKVN * CDIM * 2;
  short* wproj_t = (short*)ws; ws += (size_t)DEPTHL * CDIM * CDIM * 2;
  short* w1_t    = (short*)ws; ws += (size_t)DEPTHL * MLPD * CDIM * 2;
  short* w2_t    = (short*)ws; ws += (size_t)DEPTHL * CDIM * MLPD * 2;
  short* ybf     = (short*)ws; ws += (size_t)TOK * CDIM * 2;
  short* qkvbf   = (short*)ws; ws += (size_t)TOK * QKVN * 2;
  short* obf     = (short*)ws; ws += (size_t)TOK * CDIM * 2;
  short* f1bf    = (short*)ws; ws += (size_t)TOK * MLPD * 2;
  short* vtb     = f1bf;   // overlay: vt lifetime [vtrans, attn] disjoint from f1 [fc1, fc2]

  hipMemcpyAsync(h, x, (size_t)TOK * CDIM * sizeof(float), hipMemcpyDeviceToDevice, stream);

  wconv_t<<<dim3(QKVN / 32, CDIM / 32, DEPTHL), 256, 0, stream>>>(wqkv, wqkv_t, CDIM, QKVN);
  wconv_t<<<dim3(CDIM / 32, CDIM / 32, DEPTHL), 256, 0, stream>>>(wproj, wproj_t, CDIM, CDIM);
  wconv_t<<<dim3(MLPD / 32, CDIM / 32, DEPTHL), 256, 0, stream>>>(w1, w1_t, CDIM, MLPD);
  wconv_t<<<dim3(CDIM / 32, MLPD / 32, DEPTHL), 256, 0, stream>>>(w2, w2_t, MLPD, CDIM);

  for (int l = 0; l < DEPTHL; l++) {
    ln_fwd<<<TOK, 192, 0, stream>>>(h, ln1_g + l * CDIM, ln1_b + l * CDIM, ybf);
    gemm_bt<0><<<dim3(QKVN / 128, TOK / 128), 256, 0, stream>>>(
        ybf, wqkv_t + (size_t)l * QKVN * CDIM, nullptr, qkvbf, TOK, QKVN, CDIM);
    vtrans<<<dim3(SEQ / 32, HDIM / 32, BZ * HEADS), 256, 0, stream>>>(qkvbf, vtb);
    attn_fused4<<<dim3(SEQ / 16, BZ * HEADS), 256, 0, stream>>>(qkvbf, vtb, obf);
    gemm_bt<2><<<dim3(CDIM / 128, TOK / 128), 256, 0, stream>>>(
        obf, wproj_t + (size_t)l * CDIM * CDIM, bproj + l * CDIM, h, TOK, CDIM, CDIM);
    ln_fwd<<<TOK, 192, 0, stream>>>(h, ln2_g + l * CDIM, ln2_b + l * CDIM, ybf);
    gemm_bt<1><<<dim3(MLPD / 128, TOK / 128), 256, 0, stream>>>(
        ybf, w1_t + (size_t)l * MLPD * CDIM, b1 + l * MLPD, f1bf, TOK, MLPD, CDIM);
    gemm_bt<2><<<dim3(CDIM / 128, TOK / 128), 256, 0, stream>>>(
        f1bf, w2_t + (size_t)l * CDIM * MLPD, b2 + l * CDIM, h, TOK, CDIM, MLPD);
  }
}